// Round 4
// baseline (1032.670 us; speedup 1.0000x reference)
//
#include <hip/hip_runtime.h>
#include <hip/hip_bf16.h>
#include <math.h>

// Problem constants (match reference setup_inputs)
#define E_TOT   320000
#define NNODE   20000
#define FDIM    128
#define N3F     384
#define NRBF    20
#define OV_SIZE (NNODE * 3 * FDIM)   // out_v elements (first in d_out)
#define DMAX    16                   // max distinct nodes per 64-edge block for LDS path

typedef __attribute__((ext_vector_type(8))) short short8;   // 8 bf16 = 4 VGPRs (MFMA A/B frag)
typedef __attribute__((ext_vector_type(4))) short short4v;  // 4 bf16 = 8B
typedef __attribute__((ext_vector_type(4))) float f32x4;    // MFMA C/D frag

// round-to-nearest-even f32 -> bf16 bits
__device__ __forceinline__ short f2bf(float x) {
  union { float f; unsigned u; } v; v.f = x;
  unsigned r = (v.u + 0x7fffu + ((v.u >> 16) & 1u)) >> 16;
  return (short)r;
}

// ---------------- kernel 1: global sum of r^2 (for org_r = r / ||r||_F) ----
__global__ void sumsq_kernel(const float* __restrict__ r, float* __restrict__ ws, int n) {
  int tid = blockIdx.x * blockDim.x + threadIdx.x;
  float acc = 0.f;
  for (int i = tid; i < n; i += gridDim.x * blockDim.x) {
    float x = r[i];
    acc += x * x;
  }
  for (int off = 32; off > 0; off >>= 1) acc += __shfl_down(acc, off);
  __shared__ float s[4];
  int lane = threadIdx.x & 63, w = threadIdx.x >> 6;
  if (lane == 0) s[w] = acc;
  __syncthreads();
  if (threadIdx.x == 0) {
    float t = s[0] + s[1] + s[2] + s[3];
    unsafeAtomicAdd(ws, t);
  }
}

// ---------------- kernel 2: pre-swizzle W_phi / W_w into bf16 MFMA B-fragment order
__global__ void prep_kernel(const float* __restrict__ Wphi, const float* __restrict__ Ww,
                            short* __restrict__ frag) {
  int g = blockIdx.x * 256 + threadIdx.x;   // 30 blocks * 256 = 7680 = 120*64
  int lane = g & 63;
  int fid  = g >> 6;
  short* out = frag + (size_t)g * 8;
  if (fid < 96) {
    int ntile = fid >> 2, ks = fid & 3;
    int n  = ntile * 16 + (lane & 15);
    int kb = ks * 32 + (lane >> 4) * 8;
#pragma unroll
    for (int j = 0; j < 8; ++j) out[j] = f2bf(Wphi[(kb + j) * N3F + n]);
  } else if (fid < 120) {
    int ntile = fid - 96;
    int n  = ntile * 16 + (lane & 15);
    int kb = (lane >> 4) * 8;
#pragma unroll
    for (int j = 0; j < 8; ++j) {
      int k = kb + j;
      out[j] = (k < NRBF) ? f2bf(Ww[k * N3F + n]) : (short)0;
    }
  }
}

// ---------------- counting sort of edges by destination node ---------------
__global__ void hist_kernel(const int* __restrict__ idx, int* __restrict__ cnt) {
  int e = blockIdx.x * 256 + threadIdx.x;
  if (e < E_TOT) atomicAdd(&cnt[idx[e]], 1);
}

__global__ void scan_kernel(const int* __restrict__ cnt, int* __restrict__ cursor) {
  __shared__ int part[256];
  __shared__ int base_sh[256];
  const int t = threadIdx.x;
  int lo = t * 79; if (lo > NNODE) lo = NNODE;
  int hi = t * 79 + 79; if (hi > NNODE) hi = NNODE;
  int s = 0;
  for (int i = lo; i < hi; ++i) s += cnt[i];
  part[t] = s;
  __syncthreads();
  if (t == 0) {
    int run = 0;
    for (int i = 0; i < 256; ++i) { base_sh[i] = run; run += part[i]; }
  }
  __syncthreads();
  int run = base_sh[t];
  for (int i = lo; i < hi; ++i) { cursor[i] = run; run += cnt[i]; }
}

__global__ void scatter_kernel(const int* __restrict__ idx, int* __restrict__ cursor,
                               int* __restrict__ perm) {
  int e = blockIdx.x * 256 + threadIdx.x;
  if (e < E_TOT) {
    int p = atomicAdd(&cursor[idx[e]], 1);
    perm[p] = e;
  }
}

// ---------------- kernel 3: fused message kernel ---------------------------
// Block = 256 thr (4 waves), 64 edges/block. Wave w owns rows [16w,16w+16).
// USE_PERM=true : edges node-sorted via perm; epilogue run-merges in regs ->
//                 LDS per-node acc -> one flush per distinct node.
// USE_PERM=false: identity order; d is almost always > DMAX so the epilogue
//                 degenerates to the verified direct-atomic path.
template <bool USE_PERM>
__launch_bounds__(256, 4)
__global__ void main_kernel(const float* __restrict__ s_in, const float* __restrict__ r_in,
                            const float* __restrict__ v_in, const int* __restrict__ idx_in,
                            const float* __restrict__ bphi_in, const float* __restrict__ bw_in,
                            const short* __restrict__ frag, const float* __restrict__ ws_sumsq,
                            const int* __restrict__ perm, float* __restrict__ out) {
  // pool: staging (s tile 17408B + rbf 5120B = 22528B) ALIASED with acc (DMAX*512*4 = 32768B).
  __shared__ __align__(16) char pool[DMAX * 512 * 4];
  short* sh_s   = (short*)pool;                    // [64][136] bf16, +8 pad
  short* sh_rbf = (short*)(pool + 64 * 136 * 2);   // [64][40] bf16
  float* acc    = (float*)pool;                    // [d][4][128] f32 (after staging is dead)
  __shared__ float sh_bphi[N3F];
  __shared__ float sh_bw[N3F];
  __shared__ float sh_orgr[64][4];
  __shared__ int   sh_perm[64];
  __shared__ int   sh_lid[64];
  __shared__ int   sh_nodes[64];
  __shared__ int   sh_d;

  const int tid = threadIdx.x;
  const int e0  = blockIdx.x * 64;
  const float inv_gnorm = 1.0f / sqrtf(ws_sumsq[0]);

  // ---- per-edge prologue, rbf distributed over ALL 4 waves ----
  // er = edge row, part = which 5 of the 20 rbf values this thread computes.
  {
    const int er = tid & 63, part = tid >> 6;
    int pe = USE_PERM ? perm[e0 + er] : (e0 + er);   // global read (L2-hot), no LDS race
    float rx = r_in[pe * 3 + 0], ry = r_in[pe * 3 + 1], rz = r_in[pe * 3 + 2];
    float rn = sqrtf(rx * rx + ry * ry + rz * rz);
    float irn = 1.0f / rn;
    const float c0 = 0.62831853071795864769f;  // pi / R_CUT
    if (part == 0) {   // wave 0: bookkeeping + segment ids (tid == er here)
      sh_perm[er] = pe;
      int node = idx_in[pe];
      sh_orgr[er][0] = rx * inv_gnorm;
      sh_orgr[er][1] = ry * inv_gnorm;
      sh_orgr[er][2] = rz * inv_gnorm;
#pragma unroll
      for (int k = NRBF; k < 32; ++k) sh_rbf[er * 40 + k] = 0;
      // segment id of row t = (# of run-leading flags at positions <= t) - 1.
      // (2<<63) wraps to 0 -> all-ones mask, correct for tid=63.
      int prev = __shfl_up(node, 1);
      int flag = (er == 0) || (node != prev);
      unsigned long long m = __ballot(flag);
      int lid = (int)__popcll(m & ((2ull << er) - 1ull)) - 1;
      sh_lid[er] = lid;
      if (flag) sh_nodes[lid] = node;
      if (er == 0) sh_d = (int)__popcll(m);
    }
#pragma unroll
    for (int j = 0; j < 5; ++j) {
      int n = part * 5 + j + 1;          // 1..20 across the 4 parts
      float t = __sinf(((float)n * c0) * rn) * irn;
      float val = (t <= 5.0f) ? 0.5f * (__cosf(c0 * t) + 1.0f) : 0.0f;
      sh_rbf[er * 40 + (n - 1)] = f2bf(val);
    }
  }
  for (int j = tid; j < N3F; j += 256) {
    sh_bphi[j] = bphi_in[j];
    sh_bw[j]   = bw_in[j];
  }
  __syncthreads();

  // ---- stage s tile (gathered 512B rows via perm), coalesced float4 ----
#pragma unroll
  for (int it = 0; it < 8; ++it) {
    int idx4 = tid + it * 256;           // 2048 float4 per block
    int row = idx4 >> 5, kq = idx4 & 31;
    const float4* srow = (const float4*)(s_in + (size_t)sh_perm[row] * FDIM);
    float4 val = srow[kq];
    short4v p = { f2bf(val.x), f2bf(val.y), f2bf(val.z), f2bf(val.w) };
    *(short4v*)&sh_s[row * 136 + kq * 4] = p;
  }
  __syncthreads();

  const int wave = tid >> 6, lane = tid & 63;
  const int col  = lane & 15;     // C col within 16-tile; also A-frag row m
  const int q    = lane >> 4;     // quad

  // A fragments
  const int arow = wave * 16 + col;
  short8 a_phi[4];
#pragma unroll
  for (int ks = 0; ks < 4; ++ks)
    a_phi[ks] = *(const short8*)&sh_s[arow * 136 + ks * 32 + q * 8];
  short8 a_w = *(const short8*)&sh_rbf[arow * 40 + q * 8];

  // per-lane epilogue rows: C row = q*4 + i (4 consecutive rows)
  int   lid4[4];
  const float* vrow[4];
  float orx[4], ory[4], orz[4];
#pragma unroll
  for (int i = 0; i < 4; ++i) {
    int el = wave * 16 + q * 4 + i;
    lid4[i] = sh_lid[el];
    vrow[i] = v_in + (size_t)sh_perm[el] * (3 * FDIM);
    orx[i] = sh_orgr[el][0];
    ory[i] = sh_orgr[el][1];
    orz[i] = sh_orgr[el][2];
  }
  const int d = sh_d;
  const bool use_lds = USE_PERM && (d <= DMAX);

  __syncthreads();                 // all waves done reading sh_s/sh_rbf
  if (use_lds) {                   // zero acc (aliases staging)
    for (int j = tid; j < (d << 9); j += 256) acc[j] = 0.f;
  }
  __syncthreads();

  float* out_v = out;
  float* out_s = out + OV_SIZE;
  const short8* fp = (const short8*)frag;
  const short8* fw = fp + 96 * 64;

  // ---- software-pipelined f-loop: double-buffered v prefetch -------------
  // VISSUE(f_, ...) issues the 12 v-gather loads for iteration f_ into a
  // register buffer; they are consumed one BODY later (hidden by MFMA+epilogue).
#define VISSUE(f_, X, Y, Z)                                                   \
  { int ft_ = (f_) * 16 + col;                                                \
    _Pragma("unroll")                                                         \
    for (int i = 0; i < 4; ++i) {                                             \
      X[i] = vrow[i][ft_];                                                    \
      Y[i] = vrow[i][ft_ + FDIM];                                             \
      Z[i] = vrow[i][ft_ + 2 * FDIM];                                         \
    } }

#define BODY(f_, CX, CY, CZ, NX, NY, NZ)                                      \
  {                                                                           \
    const int fb = (f_);                                                      \
    if (fb + 1 < 8) VISSUE(fb + 1, NX, NY, NZ);  /* issue next-f v loads */   \
    const int nt0 = fb, nt1 = fb + 8, nt2 = fb + 16;                          \
    f32x4 accP0 = {0.f, 0.f, 0.f, 0.f}, accP1 = accP0, accP2 = accP0;         \
    f32x4 accW0 = accP0, accW1 = accP0, accW2 = accP0;                        \
    _Pragma("unroll")                                                         \
    for (int ks = 0; ks < 4; ++ks) {                                          \
      short8 b0 = fp[(nt0 * 4 + ks) * 64 + lane];                             \
      short8 b1 = fp[(nt1 * 4 + ks) * 64 + lane];                             \
      short8 b2 = fp[(nt2 * 4 + ks) * 64 + lane];                             \
      accP0 = __builtin_amdgcn_mfma_f32_16x16x32_bf16(a_phi[ks], b0, accP0, 0, 0, 0); \
      accP1 = __builtin_amdgcn_mfma_f32_16x16x32_bf16(a_phi[ks], b1, accP1, 0, 0, 0); \
      accP2 = __builtin_amdgcn_mfma_f32_16x16x32_bf16(a_phi[ks], b2, accP2, 0, 0, 0); \
    }                                                                         \
    accW0 = __builtin_amdgcn_mfma_f32_16x16x32_bf16(a_w, fw[nt0 * 64 + lane], accW0, 0, 0, 0); \
    accW1 = __builtin_amdgcn_mfma_f32_16x16x32_bf16(a_w, fw[nt1 * 64 + lane], accW1, 0, 0, 0); \
    accW2 = __builtin_amdgcn_mfma_f32_16x16x32_bf16(a_w, fw[nt2 * 64 + lane], accW2, 0, 0, 0); \
    const int feat = fb * 16 + col;                                           \
    const float bp0 = sh_bphi[feat], bp1 = sh_bphi[feat + 128], bp2 = sh_bphi[feat + 256]; \
    const float bw0 = sh_bw[feat],   bw1 = sh_bw[feat + 128],   bw2 = sh_bw[feat + 256];   \
    float as = 0.f, avx = 0.f, avy = 0.f, avz = 0.f;                          \
    int cur = lid4[0];                                                        \
    _Pragma("unroll")                                                         \
    for (int i = 0; i < 4; ++i) {                                             \
      float sp0 = (accW0[i] + bw0) * (accP0[i] + bp0);                        \
      float sp1 = (accW1[i] + bw1) * (accP1[i] + bp1);                        \
      float sp2 = (accW2[i] + bw2) * (accP2[i] + bp2);                        \
      float mx = sp2 * orx[i] + sp0 * CX[i];                                  \
      float my = sp2 * ory[i] + sp0 * CY[i];                                  \
      float mz = sp2 * orz[i] + sp0 * CZ[i];                                  \
      if (lid4[i] != cur) {                                                   \
        FLUSH(cur, as, avx, avy, avz);                                        \
        as = avx = avy = avz = 0.f;                                           \
        cur = lid4[i];                                                        \
      }                                                                       \
      as += sp1; avx += mx; avy += my; avz += mz;                             \
    }                                                                         \
    FLUSH(cur, as, avx, avy, avz);                                            \
  }

#define FLUSH(l_, as_, avx_, avy_, avz_)                                      \
  { const int l = (l_);                                                       \
    if (use_lds) {                                                            \
      atomicAdd(&acc[(l << 9) + feat], as_);                                  \
      atomicAdd(&acc[(l << 9) + 128 + feat], avx_);                           \
      atomicAdd(&acc[(l << 9) + 256 + feat], avy_);                           \
      atomicAdd(&acc[(l << 9) + 384 + feat], avz_);                           \
    } else {                                                                  \
      int node = sh_nodes[l];                                                 \
      unsafeAtomicAdd(&out_s[node * FDIM + feat], as_);                       \
      unsafeAtomicAdd(&out_v[(node * 3 + 0) * FDIM + feat], avx_);            \
      unsafeAtomicAdd(&out_v[(node * 3 + 1) * FDIM + feat], avy_);            \
      unsafeAtomicAdd(&out_v[(node * 3 + 2) * FDIM + feat], avz_);            \
    } }

  float Avx[4], Avy[4], Avz[4], Bvx[4], Bvy[4], Bvz[4];
  VISSUE(0, Avx, Avy, Avz);
  for (int ff = 0; ff < 8; ff += 2) {
    BODY(ff,     Avx, Avy, Avz, Bvx, Bvy, Bvz);
    BODY(ff + 1, Bvx, Bvy, Bvz, Avx, Avy, Avz);
  }
#undef BODY
#undef FLUSH
#undef VISSUE

  // ---- flush per-node LDS accumulators to global ----
  if (use_lds) {
    __syncthreads();
    for (int j = tid; j < (d << 9); j += 256) {
      int l = j >> 9, rem = j & 511, comp = rem >> 7, ft = rem & 127;
      int node = sh_nodes[l];
      float val = acc[j];
      float* dst = (comp == 0) ? &out_s[node * FDIM + ft]
                               : &out_v[(node * 3 + (comp - 1)) * FDIM + ft];
      // interior nodes (all their edges inside this block): plain store (out pre-zeroed)
      if (l > 0 && l < d - 1) *dst = val;
      else unsafeAtomicAdd(dst, val);
    }
  }
}

extern "C" void kernel_launch(void* const* d_in, const int* in_sizes, int n_in,
                              void* d_out, int out_size, void* d_ws, size_t ws_size,
                              hipStream_t stream) {
  const float* s_in  = (const float*)d_in[0];
  const float* r_in  = (const float*)d_in[1];
  const float* v_in  = (const float*)d_in[2];
  const int*   idx_i = (const int*)d_in[3];
  const float* Wphi  = (const float*)d_in[4];
  const float* bphi  = (const float*)d_in[5];
  const float* Ww    = (const float*)d_in[6];
  const float* bw    = (const float*)d_in[7];
  float* out = (float*)d_out;

  // ws layout (sorted path):
  //   [0,16)            f32 sumsq accumulator
  //   [16, 80016)       int cnt[20000]           (zeroed each launch with sumsq)
  //   [80016, 202896)   bf16 W fragments (122880 B, 16B aligned)
  //   [202896, 282896)  int cursor[20000]
  //   [282896, 1562896) int perm[320000]
  const size_t WS_NEED_SORTED = 1562896;
  const bool use_sorted = (ws_size >= WS_NEED_SORTED);

  float* ws_sumsq = (float*)d_ws;
  int*   cnt      = (int*)((char*)d_ws + 16);
  short* frag_s   = (short*)((char*)d_ws + 80016);
  int*   cursor   = (int*)((char*)d_ws + 202896);
  int*   permv    = (int*)((char*)d_ws + 282896);
  // fallback layout: [0,16) sumsq; [16, 122896) frags (round-0 footprint)
  short* frag_f   = (short*)((char*)d_ws + 16);
  short* frag     = use_sorted ? frag_s : frag_f;

  hipMemsetAsync(d_out, 0, (size_t)out_size * sizeof(float), stream);
  hipMemsetAsync(d_ws, 0, use_sorted ? 80016 : 16, stream);
  sumsq_kernel<<<480, 256, 0, stream>>>(r_in, ws_sumsq, in_sizes[1]);
  prep_kernel<<<30, 256, 0, stream>>>(Wphi, Ww, frag);
  if (use_sorted) {
    hist_kernel<<<1250, 256, 0, stream>>>(idx_i, cnt);
    scan_kernel<<<1, 256, 0, stream>>>(cnt, cursor);
    scatter_kernel<<<1250, 256, 0, stream>>>(idx_i, cursor, permv);
    main_kernel<true><<<E_TOT / 64, 256, 0, stream>>>(s_in, r_in, v_in, idx_i, bphi, bw,
                                                      frag, ws_sumsq, permv, out);
  } else {
    main_kernel<false><<<E_TOT / 64, 256, 0, stream>>>(s_in, r_in, v_in, idx_i, bphi, bw,
                                                       frag, ws_sumsq, nullptr, out);
  }
}

// Round 5
// 979.260 us; speedup vs baseline: 1.0545x; 1.0545x over previous
//
#include <hip/hip_runtime.h>
#include <hip/hip_bf16.h>
#include <math.h>

// Problem constants (match reference setup_inputs)
#define E_TOT   320000
#define NNODE   20000
#define FDIM    128
#define N3F     384
#define NRBF    20
#define OV_SIZE (NNODE * 3 * FDIM)   // out_v elements (first in d_out)
#define DMAX    12                   // max distinct nodes per 64-edge block for LDS path
                                     // (pool 24576B >= staging 22528B; ~29.5KB total LDS -> 5 blocks/CU)

typedef __attribute__((ext_vector_type(8))) short short8;   // 8 bf16 = 4 VGPRs (MFMA A/B frag)
typedef __attribute__((ext_vector_type(4))) short short4v;  // 4 bf16 = 8B
typedef __attribute__((ext_vector_type(4))) float f32x4;    // MFMA C/D frag

// round-to-nearest-even f32 -> bf16 bits
__device__ __forceinline__ short f2bf(float x) {
  union { float f; unsigned u; } v; v.f = x;
  unsigned r = (v.u + 0x7fffu + ((v.u >> 16) & 1u)) >> 16;
  return (short)r;
}

// ---------------- kernel 1: global sum of r^2 (for org_r = r / ||r||_F) ----
__global__ void sumsq_kernel(const float* __restrict__ r, float* __restrict__ ws, int n) {
  int tid = blockIdx.x * blockDim.x + threadIdx.x;
  float acc = 0.f;
  for (int i = tid; i < n; i += gridDim.x * blockDim.x) {
    float x = r[i];
    acc += x * x;
  }
  for (int off = 32; off > 0; off >>= 1) acc += __shfl_down(acc, off);
  __shared__ float s[4];
  int lane = threadIdx.x & 63, w = threadIdx.x >> 6;
  if (lane == 0) s[w] = acc;
  __syncthreads();
  if (threadIdx.x == 0) {
    float t = s[0] + s[1] + s[2] + s[3];
    unsafeAtomicAdd(ws, t);
  }
}

// ---------------- kernel 2: pre-swizzle W_phi / W_w into bf16 MFMA B-fragment order
__global__ void prep_kernel(const float* __restrict__ Wphi, const float* __restrict__ Ww,
                            short* __restrict__ frag) {
  int g = blockIdx.x * 256 + threadIdx.x;   // 30 blocks * 256 = 7680 = 120*64
  int lane = g & 63;
  int fid  = g >> 6;
  short* out = frag + (size_t)g * 8;
  if (fid < 96) {
    int ntile = fid >> 2, ks = fid & 3;
    int n  = ntile * 16 + (lane & 15);
    int kb = ks * 32 + (lane >> 4) * 8;
#pragma unroll
    for (int j = 0; j < 8; ++j) out[j] = f2bf(Wphi[(kb + j) * N3F + n]);
  } else if (fid < 120) {
    int ntile = fid - 96;
    int n  = ntile * 16 + (lane & 15);
    int kb = (lane >> 4) * 8;
#pragma unroll
    for (int j = 0; j < 8; ++j) {
      int k = kb + j;
      out[j] = (k < NRBF) ? f2bf(Ww[k * N3F + n]) : (short)0;
    }
  }
}

// ---------------- counting sort of edges by destination node ---------------
__global__ void hist_kernel(const int* __restrict__ idx, int* __restrict__ cnt) {
  int e = blockIdx.x * 256 + threadIdx.x;
  if (e < E_TOT) atomicAdd(&cnt[idx[e]], 1);
}

__global__ void scan_kernel(const int* __restrict__ cnt, int* __restrict__ cursor) {
  __shared__ int part[256];
  __shared__ int base_sh[256];
  const int t = threadIdx.x;
  int lo = t * 79; if (lo > NNODE) lo = NNODE;
  int hi = t * 79 + 79; if (hi > NNODE) hi = NNODE;
  int s = 0;
  for (int i = lo; i < hi; ++i) s += cnt[i];
  part[t] = s;
  __syncthreads();
  if (t == 0) {
    int run = 0;
    for (int i = 0; i < 256; ++i) { base_sh[i] = run; run += part[i]; }
  }
  __syncthreads();
  int run = base_sh[t];
  for (int i = lo; i < hi; ++i) { cursor[i] = run; run += cnt[i]; }
}

__global__ void scatter_kernel(const int* __restrict__ idx, int* __restrict__ cursor,
                               int* __restrict__ perm) {
  int e = blockIdx.x * 256 + threadIdx.x;
  if (e < E_TOT) {
    int p = atomicAdd(&cursor[idx[e]], 1);
    perm[p] = e;
  }
}

// ---------------- kernel 3: fused message kernel ---------------------------
// Block = 256 thr (4 waves), 64 edges/block. Wave w owns rows [16w,16w+16).
// USE_PERM=true : edges node-sorted via perm; epilogue run-merges in regs ->
//                 LDS per-node acc -> one flush per distinct node.
// USE_PERM=false: identity order; d is almost always > DMAX so the epilogue
//                 degenerates to the verified direct-atomic path.
// waves_per_eu(4,5): LDS caps at 5 blocks/CU (=5 waves/EU); forbid the compiler
// from spilling to chase 8 waves/EU (round-4 regression: spills at VGPR=64).
template <bool USE_PERM>
__attribute__((amdgpu_waves_per_eu(4, 5)))
__launch_bounds__(256)
__global__ void main_kernel(const float* __restrict__ s_in, const float* __restrict__ r_in,
                            const float* __restrict__ v_in, const int* __restrict__ idx_in,
                            const float* __restrict__ bphi_in, const float* __restrict__ bw_in,
                            const short* __restrict__ frag, const float* __restrict__ ws_sumsq,
                            const int* __restrict__ perm, float* __restrict__ out) {
  // pool: staging (s tile 17408B + rbf 5120B = 22528B) ALIASED with acc (DMAX*512*4 = 24576B).
  __shared__ __align__(16) char pool[DMAX * 512 * 4];
  short* sh_s   = (short*)pool;                    // [64][136] bf16, +8 pad
  short* sh_rbf = (short*)(pool + 64 * 136 * 2);   // [64][40] bf16
  float* acc    = (float*)pool;                    // [d][4][128] f32 (after staging is dead)
  __shared__ float sh_bphi[N3F];
  __shared__ float sh_bw[N3F];
  __shared__ float sh_orgr[64][4];
  __shared__ int   sh_perm[64];
  __shared__ int   sh_lid[64];
  __shared__ int   sh_nodes[64];
  __shared__ int   sh_d;

  const int tid = threadIdx.x;
  const int e0  = blockIdx.x * 64;
  const float inv_gnorm = 1.0f / sqrtf(ws_sumsq[0]);

  // ---- per-edge prologue, rbf distributed over ALL 4 waves ----
  {
    const int er = tid & 63, part = tid >> 6;
    int pe = USE_PERM ? perm[e0 + er] : (e0 + er);   // global read (L2-hot), no LDS race
    float rx = r_in[pe * 3 + 0], ry = r_in[pe * 3 + 1], rz = r_in[pe * 3 + 2];
    float rn = sqrtf(rx * rx + ry * ry + rz * rz);
    float irn = 1.0f / rn;
    const float c0 = 0.62831853071795864769f;  // pi / R_CUT
    if (part == 0) {   // wave 0: bookkeeping + segment ids (tid == er here)
      sh_perm[er] = pe;
      int node = idx_in[pe];
      sh_orgr[er][0] = rx * inv_gnorm;
      sh_orgr[er][1] = ry * inv_gnorm;
      sh_orgr[er][2] = rz * inv_gnorm;
#pragma unroll
      for (int k = NRBF; k < 32; ++k) sh_rbf[er * 40 + k] = 0;
      // segment id of row t = (# of run-leading flags at positions <= t) - 1.
      // (2<<63) wraps to 0 -> all-ones mask, correct for tid=63.
      int prev = __shfl_up(node, 1);
      int flag = (er == 0) || (node != prev);
      unsigned long long m = __ballot(flag);
      int lid = (int)__popcll(m & ((2ull << er) - 1ull)) - 1;
      sh_lid[er] = lid;
      if (flag) sh_nodes[lid] = node;
      if (er == 0) sh_d = (int)__popcll(m);
    }
#pragma unroll
    for (int j = 0; j < 5; ++j) {
      int n = part * 5 + j + 1;          // 1..20 across the 4 parts
      float t = __sinf(((float)n * c0) * rn) * irn;
      float val = (t <= 5.0f) ? 0.5f * (__cosf(c0 * t) + 1.0f) : 0.0f;
      sh_rbf[er * 40 + (n - 1)] = f2bf(val);
    }
  }
  for (int j = tid; j < N3F; j += 256) {
    sh_bphi[j] = bphi_in[j];
    sh_bw[j]   = bw_in[j];
  }
  __syncthreads();

  // ---- stage s tile (gathered 512B rows via perm), coalesced float4 ----
#pragma unroll
  for (int it = 0; it < 8; ++it) {
    int idx4 = tid + it * 256;           // 2048 float4 per block
    int row = idx4 >> 5, kq = idx4 & 31;
    const float4* srow = (const float4*)(s_in + (size_t)sh_perm[row] * FDIM);
    float4 val = srow[kq];
    short4v p = { f2bf(val.x), f2bf(val.y), f2bf(val.z), f2bf(val.w) };
    *(short4v*)&sh_s[row * 136 + kq * 4] = p;
  }
  __syncthreads();

  const int wave = tid >> 6, lane = tid & 63;
  const int col  = lane & 15;     // C col within 16-tile; also A-frag row m
  const int q    = lane >> 4;     // quad

  // A fragments
  const int arow = wave * 16 + col;
  short8 a_phi[4];
#pragma unroll
  for (int ks = 0; ks < 4; ++ks)
    a_phi[ks] = *(const short8*)&sh_s[arow * 136 + ks * 32 + q * 8];
  short8 a_w = *(const short8*)&sh_rbf[arow * 40 + q * 8];

  // per-lane epilogue rows: C row = q*4 + i (4 consecutive rows)
  int   lid4[4];
  const float* vrow[4];
  float orx[4], ory[4], orz[4];
#pragma unroll
  for (int i = 0; i < 4; ++i) {
    int el = wave * 16 + q * 4 + i;
    lid4[i] = sh_lid[el];
    vrow[i] = v_in + (size_t)sh_perm[el] * (3 * FDIM);
    orx[i] = sh_orgr[el][0];
    ory[i] = sh_orgr[el][1];
    orz[i] = sh_orgr[el][2];
  }
  const int d = sh_d;
  const bool use_lds = USE_PERM && (d <= DMAX);

  __syncthreads();                 // all waves done reading sh_s/sh_rbf
  if (use_lds) {                   // zero acc (aliases staging)
    for (int j = tid; j < (d << 9); j += 256) acc[j] = 0.f;
  }
  __syncthreads();

  float* out_v = out;
  float* out_s = out + OV_SIZE;
  const short8* fp = (const short8*)frag;
  const short8* fw = fp + 96 * 64;

  for (int f = 0; f < 8; ++f) {
    // keep the 4 waves lockstep: all read the same 15KB frag window -> L1-hot
    __syncthreads();

    const int feat = f * 16 + col;

    // ---- early-issue the 12 v-gathers; consumed after the MFMA section ----
    float vx[4], vy[4], vz[4];
#pragma unroll
    for (int i = 0; i < 4; ++i) {
      vx[i] = vrow[i][feat];
      vy[i] = vrow[i][feat + FDIM];
      vz[i] = vrow[i][feat + 2 * FDIM];
    }

    const int nt0 = f, nt1 = f + 8, nt2 = f + 16;
    f32x4 accP0 = {0.f, 0.f, 0.f, 0.f}, accP1 = accP0, accP2 = accP0;
    f32x4 accW0 = accP0, accW1 = accP0, accW2 = accP0;
#pragma unroll
    for (int ks = 0; ks < 4; ++ks) {
      short8 b0 = fp[(nt0 * 4 + ks) * 64 + lane];
      short8 b1 = fp[(nt1 * 4 + ks) * 64 + lane];
      short8 b2 = fp[(nt2 * 4 + ks) * 64 + lane];
      accP0 = __builtin_amdgcn_mfma_f32_16x16x32_bf16(a_phi[ks], b0, accP0, 0, 0, 0);
      accP1 = __builtin_amdgcn_mfma_f32_16x16x32_bf16(a_phi[ks], b1, accP1, 0, 0, 0);
      accP2 = __builtin_amdgcn_mfma_f32_16x16x32_bf16(a_phi[ks], b2, accP2, 0, 0, 0);
    }
    accW0 = __builtin_amdgcn_mfma_f32_16x16x32_bf16(a_w, fw[nt0 * 64 + lane], accW0, 0, 0, 0);
    accW1 = __builtin_amdgcn_mfma_f32_16x16x32_bf16(a_w, fw[nt1 * 64 + lane], accW1, 0, 0, 0);
    accW2 = __builtin_amdgcn_mfma_f32_16x16x32_bf16(a_w, fw[nt2 * 64 + lane], accW2, 0, 0, 0);

    const float bp0 = sh_bphi[feat], bp1 = sh_bphi[feat + 128], bp2 = sh_bphi[feat + 256];
    const float bw0 = sh_bw[feat],   bw1 = sh_bw[feat + 128],   bw2 = sh_bw[feat + 256];

    auto flush = [&](int l, float as, float avx, float avy, float avz) {
      if (use_lds) {
        atomicAdd(&acc[(l << 9) + feat], as);
        atomicAdd(&acc[(l << 9) + 128 + feat], avx);
        atomicAdd(&acc[(l << 9) + 256 + feat], avy);
        atomicAdd(&acc[(l << 9) + 384 + feat], avz);
      } else {
        int node = sh_nodes[l];
        unsafeAtomicAdd(&out_s[node * FDIM + feat], as);
        unsafeAtomicAdd(&out_v[(node * 3 + 0) * FDIM + feat], avx);
        unsafeAtomicAdd(&out_v[(node * 3 + 1) * FDIM + feat], avy);
        unsafeAtomicAdd(&out_v[(node * 3 + 2) * FDIM + feat], avz);
      }
    };

    // run-merged accumulation over this lane's 4 consecutive rows
    float as = 0.f, avx = 0.f, avy = 0.f, avz = 0.f;
    int cur = lid4[0];
#pragma unroll
    for (int i = 0; i < 4; ++i) {
      float sp0 = (accW0[i] + bw0) * (accP0[i] + bp0);
      float sp1 = (accW1[i] + bw1) * (accP1[i] + bp1);
      float sp2 = (accW2[i] + bw2) * (accP2[i] + bp2);
      float mx = sp2 * orx[i] + sp0 * vx[i];
      float my = sp2 * ory[i] + sp0 * vy[i];
      float mz = sp2 * orz[i] + sp0 * vz[i];
      if (lid4[i] != cur) {
        flush(cur, as, avx, avy, avz);
        as = avx = avy = avz = 0.f;
        cur = lid4[i];
      }
      as += sp1; avx += mx; avy += my; avz += mz;
    }
    flush(cur, as, avx, avy, avz);
  }

  // ---- flush per-node LDS accumulators to global ----
  if (use_lds) {
    __syncthreads();
    for (int j = tid; j < (d << 9); j += 256) {
      int l = j >> 9, rem = j & 511, comp = rem >> 7, ft = rem & 127;
      int node = sh_nodes[l];
      float val = acc[j];
      float* dst = (comp == 0) ? &out_s[node * FDIM + ft]
                               : &out_v[(node * 3 + (comp - 1)) * FDIM + ft];
      // interior nodes (all their edges inside this block): plain store (out pre-zeroed)
      if (l > 0 && l < d - 1) *dst = val;
      else unsafeAtomicAdd(dst, val);
    }
  }
}

extern "C" void kernel_launch(void* const* d_in, const int* in_sizes, int n_in,
                              void* d_out, int out_size, void* d_ws, size_t ws_size,
                              hipStream_t stream) {
  const float* s_in  = (const float*)d_in[0];
  const float* r_in  = (const float*)d_in[1];
  const float* v_in  = (const float*)d_in[2];
  const int*   idx_i = (const int*)d_in[3];
  const float* Wphi  = (const float*)d_in[4];
  const float* bphi  = (const float*)d_in[5];
  const float* Ww    = (const float*)d_in[6];
  const float* bw    = (const float*)d_in[7];
  float* out = (float*)d_out;

  // ws layout (sorted path):
  //   [0,16)            f32 sumsq accumulator
  //   [16, 80016)       int cnt[20000]           (zeroed each launch with sumsq)
  //   [80016, 202896)   bf16 W fragments (122880 B, 16B aligned)
  //   [202896, 282896)  int cursor[20000]
  //   [282896, 1562896) int perm[320000]
  const size_t WS_NEED_SORTED = 1562896;
  const bool use_sorted = (ws_size >= WS_NEED_SORTED);

  float* ws_sumsq = (float*)d_ws;
  int*   cnt      = (int*)((char*)d_ws + 16);
  short* frag_s   = (short*)((char*)d_ws + 80016);
  int*   cursor   = (int*)((char*)d_ws + 202896);
  int*   permv    = (int*)((char*)d_ws + 282896);
  // fallback layout: [0,16) sumsq; [16, 122896) frags (round-0 footprint)
  short* frag_f   = (short*)((char*)d_ws + 16);
  short* frag     = use_sorted ? frag_s : frag_f;

  hipMemsetAsync(d_out, 0, (size_t)out_size * sizeof(float), stream);
  hipMemsetAsync(d_ws, 0, use_sorted ? 80016 : 16, stream);
  sumsq_kernel<<<480, 256, 0, stream>>>(r_in, ws_sumsq, in_sizes[1]);
  prep_kernel<<<30, 256, 0, stream>>>(Wphi, Ww, frag);
  if (use_sorted) {
    hist_kernel<<<1250, 256, 0, stream>>>(idx_i, cnt);
    scan_kernel<<<1, 256, 0, stream>>>(cnt, cursor);
    scatter_kernel<<<1250, 256, 0, stream>>>(idx_i, cursor, permv);
    main_kernel<true><<<E_TOT / 64, 256, 0, stream>>>(s_in, r_in, v_in, idx_i, bphi, bw,
                                                      frag, ws_sumsq, permv, out);
  } else {
    main_kernel<false><<<E_TOT / 64, 256, 0, stream>>>(s_in, r_in, v_in, idx_i, bphi, bw,
                                                       frag, ws_sumsq, nullptr, out);
  }
}